// Round 5
// baseline (531.034 us; speedup 1.0000x reference)
//
#include <hip/hip_runtime.h>
#include <hip/hip_bf16.h>
#include <hip/hip_fp16.h>

#define NN 100000
#define NG 256
#define NE 800000

constexpr int F0 = 114;   // x features
constexpr int F1 = 230;   // layer1 output features
constexpr int F2 = 115;   // layer2 output features
constexpr int MPAD = 100096;  // 782 * 128

typedef __attribute__((ext_vector_type(8))) short s8b;        // 8 bf16 (MFMA operand)
typedef __attribute__((ext_vector_type(4))) float f32x4;      // MFMA acc
typedef __attribute__((ext_vector_type(8))) unsigned short u16x8;

__device__ __forceinline__ unsigned short f2bf(float x) {
  __hip_bfloat16 h = __float2bfloat16(x);
  return *(unsigned short*)&h;
}
__device__ __forceinline__ float bf2f(unsigned short u) {
  __hip_bfloat16 h = *(__hip_bfloat16*)&u;
  return __bfloat162float(h);
}

// ---------------- degree / CSR build ----------------

__global__ void k_count(const int* __restrict__ dst, int* __restrict__ cnt) {
  int e = blockIdx.x * blockDim.x + threadIdx.x;
  if (e < NE) atomicAdd(&cnt[dst[e]], 1);
}

__global__ void k_dinv(const int* __restrict__ cnt, float* __restrict__ dinv) {
  int i = blockIdx.x * blockDim.x + threadIdx.x;
  if (i < NN) dinv[i] = rsqrtf((float)cnt[i] + 1.0f);
}

constexpr int SCAN_T = 256;
constexpr int SCAN_E = 1024;
constexpr int NB = (NN + SCAN_E - 1) / SCAN_E;  // 98

__global__ void k_scan1(const int* __restrict__ cnt, int* __restrict__ off,
                        int* __restrict__ bsum) {
  __shared__ int s[SCAN_T];
  int b = blockIdx.x, t = threadIdx.x;
  int base = b * SCAN_E + t * 4;
  int v0 = 0, v1 = 0, v2 = 0, v3 = 0;
  if (base + 0 < NN) v0 = cnt[base + 0];
  if (base + 1 < NN) v1 = cnt[base + 1];
  if (base + 2 < NN) v2 = cnt[base + 2];
  if (base + 3 < NN) v3 = cnt[base + 3];
  int sum = v0 + v1 + v2 + v3;
  s[t] = sum;
  __syncthreads();
  for (int ofs = 1; ofs < SCAN_T; ofs <<= 1) {
    int x = (t >= ofs) ? s[t - ofs] : 0;
    __syncthreads();
    s[t] += x;
    __syncthreads();
  }
  int excl = s[t] - sum;
  if (base + 0 < NN) off[base + 0] = excl;
  if (base + 1 < NN) off[base + 1] = excl + v0;
  if (base + 2 < NN) off[base + 2] = excl + v0 + v1;
  if (base + 3 < NN) off[base + 3] = excl + v0 + v1 + v2;
  if (t == SCAN_T - 1) bsum[b] = s[t];
}

__global__ void k_scan2(int* bsum) {
  if (threadIdx.x == 0) {
    int run = 0;
    for (int i = 0; i < NB; ++i) { int v = bsum[i]; bsum[i] = run; run += v; }
  }
}

__global__ void k_scan3(int* __restrict__ off, const int* __restrict__ bsum,
                        int* __restrict__ cur) {
  int i = blockIdx.x * blockDim.x + threadIdx.x;
  if (i < NN) {
    int v = off[i] + bsum[i / SCAN_E];
    off[i] = v;
    cur[i] = v;
  }
  if (i == NN) off[NN] = NE;
}

__global__ void k_place(const int* __restrict__ src, const int* __restrict__ dst,
                        int* __restrict__ cur, int* __restrict__ srcs) {
  int e = blockIdx.x * blockDim.x + threadIdx.x;
  if (e >= NE) return;
  int p = atomicAdd(&cur[dst[e]], 1);
  srcs[p] = src[e];
}

// ---------------- fp16 gather tables (dinv pre-folded) ----------------

// xd[n,f] = fp16(x[n,f] * dinv[n]), padded to 128 cols
__global__ void k_prepx(const float* __restrict__ x, const float* __restrict__ dinv,
                        __half* __restrict__ xd) {
  int n = blockIdx.x, f = threadIdx.x;  // 128 threads
  float v = (f < F0) ? x[(size_t)n * F0 + f] * dinv[n] : 0.0f;
  xd[(size_t)n * 128 + f] = __float2half(v);
}

// aggX[n] = dinv[n] * (xd[n] + sum_j xd[srcs[j]]), output split bf16 hi/lo
__global__ void k_gather1(const __half* __restrict__ xd, const float* __restrict__ dinv,
                          const int* __restrict__ off, const int* __restrict__ srcs,
                          unsigned short* __restrict__ oh, unsigned short* __restrict__ ol) {
  int n = blockIdx.x, f = threadIdx.x;  // 128 threads
  float acc = __half2float(xd[(size_t)n * 128 + f]);
  int j0 = off[n], j1 = off[n + 1];
  for (int j = j0; j < j1; ++j)
    acc += __half2float(xd[(size_t)srcs[j] * 128 + f]);
  acc *= dinv[n];
  unsigned short h = f2bf(acc);
  unsigned short l = f2bf(acc - bf2f(h));
  oh[(size_t)n * 128 + f] = h;
  ol[(size_t)n * 128 + f] = l;
}

// agg2[n] = dinv[n] * (td[n] + sum_j td[srcs[j]]), f32 out for pool
__global__ void k_gather2(const __half* __restrict__ td, const float* __restrict__ dinv,
                          const int* __restrict__ off, const int* __restrict__ srcs,
                          float* __restrict__ agg2) {
  int n = blockIdx.x, f = threadIdx.x;  // 128 threads
  if (f >= F2) return;
  float acc = __half2float(td[(size_t)n * 128 + f]);
  int j0 = off[n], j1 = off[n + 1];
  for (int j = j0; j < j1; ++j)
    acc += __half2float(td[(size_t)srcs[j] * 128 + f]);
  agg2[(size_t)n * 128 + f] = acc * dinv[n];
}

// ---------------- weight split+transpose prep: Bt[n][k] ----------------

__global__ void k_prepB(const float* __restrict__ W, unsigned short* __restrict__ Bh,
                        unsigned short* __restrict__ Bl, int K, int N, int KP) {
  int n = blockIdx.x, k = threadIdx.x;  // blockDim.x == KP
  float v = (k < K && n < N) ? W[(size_t)k * N + n] : 0.0f;
  unsigned short h = f2bf(v);
  unsigned short l = f2bf(v - bf2f(h));
  Bh[(size_t)n * KP + k] = h;
  Bl[(size_t)n * KP + k] = l;
}

// ---------------- bf16x3 MFMA GEMM: C = A @ Bt^T ----------------
// SPLIT: +bias, relu, split bf16 hi/lo out. !SPLIT: *dscale[m], fp16 out.
// 128x128 tile, 4 waves, BK=64 chunks -> LDS 73.7 KB -> 2 blocks/CU.

template <int KC64, bool SPLIT>
__global__ __launch_bounds__(256) void k_mgemm(
    const unsigned short* __restrict__ Ah, const unsigned short* __restrict__ Al,
    const unsigned short* __restrict__ Bh, const unsigned short* __restrict__ Bl,
    const float* __restrict__ bias, const float* __restrict__ dscale,
    int Nvalid, int M,
    __half* __restrict__ Cf16, unsigned short* __restrict__ Ch, unsigned short* __restrict__ Cl) {
  constexpr int KP = KC64 * 64;
  constexpr int LD = 72;  // ushort stride: 144B row step -> 2-way bank aliasing (free)
  __shared__ unsigned short Ash[128 * LD];
  __shared__ unsigned short Asl[128 * LD];
  __shared__ unsigned short Bsh[128 * LD];
  __shared__ unsigned short Bsl[128 * LD];

  int t = threadIdx.x;
  int m0 = blockIdx.y * 128, n0 = blockIdx.x * 128;
  int lane = t & 63, w = t >> 6;
  int wr = (w >> 1) * 64, wc = (w & 1) * 64;
  int r = lane & 15, kb = (lane >> 4) * 8;

  f32x4 acc[4][4];
#pragma unroll
  for (int i = 0; i < 4; ++i)
#pragma unroll
    for (int j = 0; j < 4; ++j) acc[i][j] = (f32x4){0.f, 0.f, 0.f, 0.f};

  int srow = t >> 1, shalf = t & 1;  // 128 rows x 2 halves (32 ushort each)
  int slo = srow * LD + shalf * 32;

  for (int kc = 0; kc < KC64; ++kc) {
    if (kc) __syncthreads();
    size_t ga = (size_t)(m0 + srow) * KP + kc * 64 + shalf * 32;
    size_t gb = (size_t)(n0 + srow) * KP + kc * 64 + shalf * 32;
#pragma unroll
    for (int v = 0; v < 4; ++v) {
      *(u16x8*)&Ash[slo + v * 8] = *(const u16x8*)&Ah[ga + v * 8];
      *(u16x8*)&Asl[slo + v * 8] = *(const u16x8*)&Al[ga + v * 8];
      *(u16x8*)&Bsh[slo + v * 8] = *(const u16x8*)&Bh[gb + v * 8];
      *(u16x8*)&Bsl[slo + v * 8] = *(const u16x8*)&Bl[gb + v * 8];
    }
    __syncthreads();

#pragma unroll
    for (int ks = 0; ks < 2; ++ks) {
      int col = ks * 32 + kb;
      s8b ah[4], al[4], bh[4], bl[4];
#pragma unroll
      for (int i = 0; i < 4; ++i) {
        ah[i] = *(const s8b*)&Ash[(wr + i * 16 + r) * LD + col];
        al[i] = *(const s8b*)&Asl[(wr + i * 16 + r) * LD + col];
        bh[i] = *(const s8b*)&Bsh[(wc + i * 16 + r) * LD + col];
        bl[i] = *(const s8b*)&Bsl[(wc + i * 16 + r) * LD + col];
      }
#pragma unroll
      for (int i = 0; i < 4; ++i)
#pragma unroll
        for (int j = 0; j < 4; ++j)
          acc[i][j] = __builtin_amdgcn_mfma_f32_16x16x32_bf16(ah[i], bl[j], acc[i][j], 0, 0, 0);
#pragma unroll
      for (int i = 0; i < 4; ++i)
#pragma unroll
        for (int j = 0; j < 4; ++j)
          acc[i][j] = __builtin_amdgcn_mfma_f32_16x16x32_bf16(al[i], bh[j], acc[i][j], 0, 0, 0);
#pragma unroll
      for (int i = 0; i < 4; ++i)
#pragma unroll
        for (int j = 0; j < 4; ++j)
          acc[i][j] = __builtin_amdgcn_mfma_f32_16x16x32_bf16(ah[i], bh[j], acc[i][j], 0, 0, 0);
    }
  }

  // epilogue: C/D layout col = lane&15, row = (lane>>4)*4 + q  [m89/m91]
  int rq = (lane >> 4) * 4;
#pragma unroll
  for (int i = 0; i < 4; ++i) {
#pragma unroll
    for (int j = 0; j < 4; ++j) {
      int n = n0 + wc + j * 16 + r;
#pragma unroll
      for (int q = 0; q < 4; ++q) {
        int m = m0 + wr + i * 16 + rq + q;
        if (m >= M) continue;
        float v = acc[i][j][q];
        if constexpr (SPLIT) {
          v = (n < Nvalid) ? fmaxf(v + bias[n], 0.0f) : 0.0f;
          unsigned short h = f2bf(v);
          unsigned short l = f2bf(v - bf2f(h));
          Ch[(size_t)m * 256 + n] = h;
          Cl[(size_t)m * 256 + n] = l;
        } else {
          Cf16[(size_t)m * 128 + n] = __float2half(v * dscale[m]);
        }
      }
    }
  }
}

// ---------------- fused relu(agg2+b2) + segmented max-pool ----------------

constexpr int POOL_CHUNK = 256;

__global__ void k_pool(const float* __restrict__ agg2, const float* __restrict__ b2,
                       const int* __restrict__ batch, float* pooled) {
  int f = threadIdx.x;
  if (f >= F2) return;
  float b = b2[f];
  int n0 = blockIdx.x * POOL_CHUNK;
  int n1 = min(n0 + POOL_CHUNK, NN);
  int curg = -1;
  float vmax = 0.0f;
  for (int n = n0; n < n1; ++n) {
    int g = batch[n];
    if (g != curg) {
      if (curg >= 0 && vmax > 0.0f)
        atomicMax((int*)&pooled[curg * F2 + f], __float_as_int(vmax));
      curg = g;
      vmax = 0.0f;
    }
    float v = agg2[(size_t)n * 128 + f] + b;
    vmax = fmaxf(vmax, v);
  }
  if (curg >= 0 && vmax > 0.0f)
    atomicMax((int*)&pooled[curg * F2 + f], __float_as_int(vmax));
}

// ---------------- tiny MLP head: 115 -> 64 -> 32 -> 1 ----------------

__global__ void k_mlp(const float* __restrict__ pooled,
                      const float* __restrict__ Wg, const float* __restrict__ bg,
                      const float* __restrict__ Wf, const float* __restrict__ bf,
                      const float* __restrict__ Wo, const float* __restrict__ bo,
                      float* __restrict__ out) {
  __shared__ float sp[F2];
  __shared__ float sg[64];
  __shared__ float sf[32];
  int g = blockIdx.x, t = threadIdx.x;
  for (int f = t; f < F2; f += 64) sp[f] = pooled[g * F2 + f];
  __syncthreads();
  float a = bg[t];
  for (int k = 0; k < F2; ++k) a += sp[k] * Wg[k * 64 + t];
  sg[t] = fmaxf(a, 0.0f);
  __syncthreads();
  if (t < 32) {
    float c = bf[t];
    for (int k = 0; k < 64; ++k) c += sg[k] * Wf[k * 32 + t];
    sf[t] = fmaxf(c, 0.0f);
  }
  __syncthreads();
  if (t == 0) {
    float c = bo[0];
    for (int k = 0; k < 32; ++k) c += sf[k] * Wo[k];
    out[g] = c;
  }
}

// ---------------- launch ----------------

extern "C" void kernel_launch(void* const* d_in, const int* in_sizes, int n_in,
                              void* d_out, int out_size, void* d_ws, size_t ws_size,
                              hipStream_t stream) {
  const float* x  = (const float*)d_in[0];
  const int* ei   = (const int*)d_in[1];
  const int* batch = (const int*)d_in[2];
  const float* W1 = (const float*)d_in[3];
  const float* b1 = (const float*)d_in[4];
  const float* W2 = (const float*)d_in[5];
  const float* b2 = (const float*)d_in[6];
  const float* Wg = (const float*)d_in[7];
  const float* bg = (const float*)d_in[8];
  const float* Wf = (const float*)d_in[9];
  const float* bf = (const float*)d_in[10];
  const float* Wo = (const float*)d_in[11];
  const float* bo = (const float*)d_in[12];
  const int* src = ei;
  const int* dst = ei + NE;

  char* p = (char*)d_ws;
  auto alloc4 = [&](size_t units) { void* r = p; p += units * 4; return r; };
  float* dinv  = (float*)alloc4(100224);
  int* cnt     = (int*)alloc4(100224);
  int* off     = (int*)alloc4(100352);
  int* cur     = (int*)alloc4(100224);
  int* bsum    = (int*)alloc4(128);
  int* srcs    = (int*)alloc4(NE);
  __half* xd   = (__half*)alloc4((size_t)NN * 128 / 2);                   // 25.6MB
  __half* td   = (__half*)alloc4((size_t)MPAD * 128 / 2);                 // 25.6MB
  unsigned short* A1h = (unsigned short*)alloc4((size_t)MPAD * 128 / 2);  // 25.6MB
  unsigned short* A1l = (unsigned short*)alloc4((size_t)MPAD * 128 / 2);
  unsigned short* Bt1h = (unsigned short*)alloc4(256 * 128 / 2);
  unsigned short* Bt1l = (unsigned short*)alloc4(256 * 128 / 2);
  unsigned short* Bt2h = (unsigned short*)alloc4(128 * 256 / 2);
  unsigned short* Bt2l = (unsigned short*)alloc4(128 * 256 / 2);
  unsigned short* h1h = (unsigned short*)alloc4((size_t)MPAD * 256 / 2);  // 51.2MB
  unsigned short* h1l = (unsigned short*)alloc4((size_t)MPAD * 256 / 2);
  float* pooled = (float*)alloc4((size_t)NG * F2);
  float* agg2   = (float*)A1h;  // alias: A1 dead after GEMM1 (spans A1h+A1l)

  hipMemsetAsync(cnt, 0, 100224 * sizeof(int), stream);
  hipMemsetAsync(pooled, 0, (size_t)NG * F2 * sizeof(float), stream);

  // CSR build (shared by both conv layers)
  k_count<<<(NE + 255) / 256, 256, 0, stream>>>(dst, cnt);
  k_dinv<<<(NN + 255) / 256, 256, 0, stream>>>(cnt, dinv);
  k_scan1<<<NB, SCAN_T, 0, stream>>>(cnt, off, bsum);
  k_scan2<<<1, 64, 0, stream>>>(bsum);
  k_scan3<<<(NN + 256) / 256, 256, 0, stream>>>(off, bsum, cur);
  k_place<<<(NE + 255) / 256, 256, 0, stream>>>(src, dst, cur, srcs);

  // weight prep (bf16 hi/lo, transposed, zero-padded)
  k_prepB<<<256, 128, 0, stream>>>(W1, Bt1h, Bt1l, F0, F1, 128);
  k_prepB<<<128, 256, 0, stream>>>(W2, Bt2h, Bt2l, F1, F2, 256);

  // layer 1: fp16 table, gather, MFMA GEMM -> h1 hi/lo
  k_prepx<<<NN, 128, 0, stream>>>(x, dinv, xd);
  k_gather1<<<NN, 128, 0, stream>>>(xd, dinv, off, srcs, A1h, A1l);
  k_mgemm<2, true><<<dim3(2, MPAD / 128), 256, 0, stream>>>(
      A1h, A1l, Bt1h, Bt1l, b1, nullptr, F1, NN, nullptr, h1h, h1l);

  // layer 2: MFMA GEMM -> td (fp16, dinv folded), then gather
  k_mgemm<4, false><<<dim3(1, MPAD / 128), 256, 0, stream>>>(
      h1h, h1l, Bt2h, Bt2l, nullptr, dinv, F2, NN, td, nullptr, nullptr);
  k_gather2<<<NN, 128, 0, stream>>>(td, dinv, off, srcs, agg2);

  // fused relu(agg2 + b2) + per-graph max pool
  k_pool<<<(NN + POOL_CHUNK - 1) / POOL_CHUNK, 128, 0, stream>>>(agg2, b2, batch, pooled);

  // head MLP
  k_mlp<<<NG, 64, 0, stream>>>(pooled, Wg, bg, Wf, bf, Wo, bo, (float*)d_out);
}

// Round 6
// 473.777 us; speedup vs baseline: 1.1209x; 1.1209x over previous
//
#include <hip/hip_runtime.h>
#include <hip/hip_bf16.h>
#include <hip/hip_fp16.h>

#define NN 100000
#define NG 256
#define NE 800000

constexpr int F0 = 114;   // x features
constexpr int F1 = 230;   // layer1 output features
constexpr int F2 = 115;   // layer2 output features
constexpr int MPAD = 100096;  // 782 * 128

typedef _Float16 __attribute__((ext_vector_type(8))) f16x8;   // MFMA operand
typedef __attribute__((ext_vector_type(4))) float f32x4;      // MFMA acc
typedef __attribute__((ext_vector_type(8))) unsigned short u16x8;

__device__ __forceinline__ unsigned short f2h_bits(float x) {
  _Float16 h = (_Float16)x;
  return __builtin_bit_cast(unsigned short, h);
}
__device__ __forceinline__ float h_bits2f(unsigned short u) {
  return (float)__builtin_bit_cast(_Float16, u);
}

// ---------------- degree / CSR build ----------------

__global__ void k_count(const int* __restrict__ dst, int* __restrict__ cnt) {
  int e = blockIdx.x * blockDim.x + threadIdx.x;
  if (e < NE) atomicAdd(&cnt[dst[e]], 1);
}

__global__ void k_dinv(const int* __restrict__ cnt, float* __restrict__ dinv) {
  int i = blockIdx.x * blockDim.x + threadIdx.x;
  if (i < NN) dinv[i] = rsqrtf((float)cnt[i] + 1.0f);
}

constexpr int SCAN_T = 256;
constexpr int SCAN_E = 1024;
constexpr int NB = (NN + SCAN_E - 1) / SCAN_E;  // 98

__global__ void k_scan1(const int* __restrict__ cnt, int* __restrict__ off,
                        int* __restrict__ bsum) {
  __shared__ int s[SCAN_T];
  int b = blockIdx.x, t = threadIdx.x;
  int base = b * SCAN_E + t * 4;
  int v0 = 0, v1 = 0, v2 = 0, v3 = 0;
  if (base + 0 < NN) v0 = cnt[base + 0];
  if (base + 1 < NN) v1 = cnt[base + 1];
  if (base + 2 < NN) v2 = cnt[base + 2];
  if (base + 3 < NN) v3 = cnt[base + 3];
  int sum = v0 + v1 + v2 + v3;
  s[t] = sum;
  __syncthreads();
  for (int ofs = 1; ofs < SCAN_T; ofs <<= 1) {
    int x = (t >= ofs) ? s[t - ofs] : 0;
    __syncthreads();
    s[t] += x;
    __syncthreads();
  }
  int excl = s[t] - sum;
  if (base + 0 < NN) off[base + 0] = excl;
  if (base + 1 < NN) off[base + 1] = excl + v0;
  if (base + 2 < NN) off[base + 2] = excl + v0 + v1;
  if (base + 3 < NN) off[base + 3] = excl + v0 + v1 + v2;
  if (t == SCAN_T - 1) bsum[b] = s[t];
}

__global__ void k_scan2(int* bsum) {
  if (threadIdx.x == 0) {
    int run = 0;
    for (int i = 0; i < NB; ++i) { int v = bsum[i]; bsum[i] = run; run += v; }
  }
}

__global__ void k_scan3(int* __restrict__ off, const int* __restrict__ bsum,
                        int* __restrict__ cur) {
  int i = blockIdx.x * blockDim.x + threadIdx.x;
  if (i < NN) {
    int v = off[i] + bsum[i / SCAN_E];
    off[i] = v;
    cur[i] = v;
  }
  if (i == NN) off[NN] = NE;
}

__global__ void k_place(const int* __restrict__ src, const int* __restrict__ dst,
                        int* __restrict__ cur, int* __restrict__ srcs) {
  int e = blockIdx.x * blockDim.x + threadIdx.x;
  if (e >= NE) return;
  int p = atomicAdd(&cur[dst[e]], 1);
  srcs[p] = src[e];
}

// ---------------- fp16 tables ----------------

// xd[n,f] = fp16(x[n,f] * dinv[n]), padded to 128 cols
__global__ void k_prepx(const float* __restrict__ x, const float* __restrict__ dinv,
                        unsigned short* __restrict__ xd) {
  int n = blockIdx.x, f = threadIdx.x;  // 128 threads
  float v = (f < F0) ? x[(size_t)n * F0 + f] * dinv[n] : 0.0f;
  xd[(size_t)n * 128 + f] = f2h_bits(v);
}

// aggX[n] = fp16( dinv[n] * (xd[n] + sum_j xd[srcs[j]]) )
__global__ void k_gather1(const unsigned short* __restrict__ xd, const float* __restrict__ dinv,
                          const int* __restrict__ off, const int* __restrict__ srcs,
                          unsigned short* __restrict__ aggX) {
  int n = blockIdx.x, f = threadIdx.x;  // 128 threads
  float acc = h_bits2f(xd[(size_t)n * 128 + f]);
  int j0 = off[n], j1 = off[n + 1];
  for (int j = j0; j < j1; ++j)
    acc += h_bits2f(xd[(size_t)srcs[j] * 128 + f]);
  aggX[(size_t)n * 128 + f] = f2h_bits(acc * dinv[n]);
}

// agg2[n] = dinv[n] * (td[n] + sum_j td[srcs[j]]), f32 out for pool
__global__ void k_gather2(const unsigned short* __restrict__ td, const float* __restrict__ dinv,
                          const int* __restrict__ off, const int* __restrict__ srcs,
                          float* __restrict__ agg2) {
  int n = blockIdx.x, f = threadIdx.x;  // 128 threads
  if (f >= F2) return;
  float acc = h_bits2f(td[(size_t)n * 128 + f]);
  int j0 = off[n], j1 = off[n + 1];
  for (int j = j0; j < j1; ++j)
    acc += h_bits2f(td[(size_t)srcs[j] * 128 + f]);
  agg2[(size_t)n * 128 + f] = acc * dinv[n];
}

// ---------------- weight split+transpose prep: Bt[n][k], fp16 hi/lo ----------------

__global__ void k_prepB(const float* __restrict__ W, unsigned short* __restrict__ Bh,
                        unsigned short* __restrict__ Bl, int K, int N, int KP) {
  int n = blockIdx.x, k = threadIdx.x;  // blockDim.x == KP
  float v = (k < K && n < N) ? W[(size_t)k * N + n] : 0.0f;
  unsigned short h = f2h_bits(v);
  unsigned short l = f2h_bits(v - h_bits2f(h));
  Bh[(size_t)n * KP + k] = h;
  Bl[(size_t)n * KP + k] = l;
}

// ---------------- fp16x2 MFMA GEMM: C = A @ (Bh+Bl)^T ----------------
// A fp16 single (exact as stored); weights fp16 hi/lo (~22-bit).
// L1: +bias, relu, out stride 256 at col n0. !L1: *dscale[m], out stride 128.
// 128x128 tile, 4 waves, BK=64 chunks. LDS 55.3 KB -> 2 blocks/CU.

template <int KC64, bool L1>
__global__ __launch_bounds__(256) void k_mgemm(
    const unsigned short* __restrict__ A,
    const unsigned short* __restrict__ Bh, const unsigned short* __restrict__ Bl,
    const float* __restrict__ bias, const float* __restrict__ dscale,
    int Nvalid, unsigned short* __restrict__ C) {
  constexpr int KP = KC64 * 64;
  constexpr int LD = 72;  // ushort stride: 144B rows -> 2-way bank aliasing (free)
  __shared__ unsigned short lds[3 * 128 * LD];  // As | Bsh | Bsl; epilogue reuses
  unsigned short* As  = lds;
  unsigned short* Bsh = lds + 128 * LD;
  unsigned short* Bsl = lds + 2 * 128 * LD;

  int t = threadIdx.x;
  int m0 = blockIdx.y * 128, n0 = blockIdx.x * 128;
  int lane = t & 63, w = t >> 6;
  int wr = (w >> 1) * 64, wc = (w & 1) * 64;
  int r = lane & 15, kb = (lane >> 4) * 8;

  f32x4 acc[4][4];
#pragma unroll
  for (int i = 0; i < 4; ++i)
#pragma unroll
    for (int j = 0; j < 4; ++j) acc[i][j] = (f32x4){0.f, 0.f, 0.f, 0.f};

  int srow = t >> 1, shalf = t & 1;  // 128 rows x 2 halves (32 ushort each)
  int slo = srow * LD + shalf * 32;

  for (int kc = 0; kc < KC64; ++kc) {
    if (kc) __syncthreads();
    size_t ga = (size_t)(m0 + srow) * KP + kc * 64 + shalf * 32;
    size_t gb = (size_t)(n0 + srow) * KP + kc * 64 + shalf * 32;
#pragma unroll
    for (int v = 0; v < 4; ++v) {
      *(u16x8*)&As[slo + v * 8]  = *(const u16x8*)&A[ga + v * 8];
      *(u16x8*)&Bsh[slo + v * 8] = *(const u16x8*)&Bh[gb + v * 8];
      *(u16x8*)&Bsl[slo + v * 8] = *(const u16x8*)&Bl[gb + v * 8];
    }
    __syncthreads();

#pragma unroll
    for (int ks = 0; ks < 2; ++ks) {
      int col = ks * 32 + kb;
      f16x8 a[4], bh[4], bl[4];
#pragma unroll
      for (int i = 0; i < 4; ++i) {
        a[i]  = *(const f16x8*)&As[(wr + i * 16 + r) * LD + col];
        bh[i] = *(const f16x8*)&Bsh[(wc + i * 16 + r) * LD + col];
        bl[i] = *(const f16x8*)&Bsl[(wc + i * 16 + r) * LD + col];
      }
      // lo pass first (small terms), then hi
#pragma unroll
      for (int i = 0; i < 4; ++i)
#pragma unroll
        for (int j = 0; j < 4; ++j)
          acc[i][j] = __builtin_amdgcn_mfma_f32_16x16x32_f16(a[i], bl[j], acc[i][j], 0, 0, 0);
#pragma unroll
      for (int i = 0; i < 4; ++i)
#pragma unroll
        for (int j = 0; j < 4; ++j)
          acc[i][j] = __builtin_amdgcn_mfma_f32_16x16x32_f16(a[i], bh[j], acc[i][j], 0, 0, 0);
    }
  }

  // epilogue: stage fp16 tile in LDS (aliases staging bufs), write coalesced.
  // C/D layout: col = lane&15, row = (lane>>4)*4 + q  [m89/m91]
  __syncthreads();
  constexpr int SW = 136;  // 272B rows: 16B-aligned, 2-way bank aliasing
  unsigned short* sw = lds;
  int rq = (lane >> 4) * 4;
#pragma unroll
  for (int i = 0; i < 4; ++i) {
#pragma unroll
    for (int j = 0; j < 4; ++j) {
      int nl = wc + j * 16 + r;
#pragma unroll
      for (int q = 0; q < 4; ++q) {
        int ml = wr + i * 16 + rq + q;
        float v = acc[i][j][q];
        if constexpr (L1) {
          int n = n0 + nl;
          v = (n < Nvalid) ? fmaxf(v + bias[n], 0.0f) : 0.0f;
        } else {
          v *= dscale[m0 + ml];
        }
        sw[ml * SW + nl] = f2h_bits(v);
      }
    }
  }
  __syncthreads();
  int row = t >> 1, half = t & 1;
  const unsigned short* s = &sw[row * SW + half * 64];
  size_t dst = L1 ? ((size_t)(m0 + row) * 256 + n0 + half * 64)
                  : ((size_t)(m0 + row) * 128 + half * 64);
#pragma unroll
  for (int v = 0; v < 8; ++v)
    *(u16x8*)&C[dst + v * 8] = *(const u16x8*)&s[v * 8];
}

// ---------------- fused relu(agg2+b2) + segmented max-pool ----------------

constexpr int POOL_CHUNK = 256;

__global__ void k_pool(const float* __restrict__ agg2, const float* __restrict__ b2,
                       const int* __restrict__ batch, float* pooled) {
  int f = threadIdx.x;
  if (f >= F2) return;
  float b = b2[f];
  int n0 = blockIdx.x * POOL_CHUNK;
  int n1 = min(n0 + POOL_CHUNK, NN);
  int curg = -1;
  float vmax = 0.0f;
  for (int n = n0; n < n1; ++n) {
    int g = batch[n];
    if (g != curg) {
      if (curg >= 0 && vmax > 0.0f)
        atomicMax((int*)&pooled[curg * F2 + f], __float_as_int(vmax));
      curg = g;
      vmax = 0.0f;
    }
    float v = agg2[(size_t)n * 128 + f] + b;
    vmax = fmaxf(vmax, v);
  }
  if (curg >= 0 && vmax > 0.0f)
    atomicMax((int*)&pooled[curg * F2 + f], __float_as_int(vmax));
}

// ---------------- tiny MLP head: 115 -> 64 -> 32 -> 1 ----------------

__global__ void k_mlp(const float* __restrict__ pooled,
                      const float* __restrict__ Wg, const float* __restrict__ bg,
                      const float* __restrict__ Wf, const float* __restrict__ bf,
                      const float* __restrict__ Wo, const float* __restrict__ bo,
                      float* __restrict__ out) {
  __shared__ float sp[F2];
  __shared__ float sg[64];
  __shared__ float sf[32];
  int g = blockIdx.x, t = threadIdx.x;
  for (int f = t; f < F2; f += 64) sp[f] = pooled[g * F2 + f];
  __syncthreads();
  float a = bg[t];
  for (int k = 0; k < F2; ++k) a += sp[k] * Wg[k * 64 + t];
  sg[t] = fmaxf(a, 0.0f);
  __syncthreads();
  if (t < 32) {
    float c = bf[t];
    for (int k = 0; k < 64; ++k) c += sg[k] * Wf[k * 32 + t];
    sf[t] = fmaxf(c, 0.0f);
  }
  __syncthreads();
  if (t == 0) {
    float c = bo[0];
    for (int k = 0; k < 32; ++k) c += sf[k] * Wo[k];
    out[g] = c;
  }
}

// ---------------- launch ----------------

extern "C" void kernel_launch(void* const* d_in, const int* in_sizes, int n_in,
                              void* d_out, int out_size, void* d_ws, size_t ws_size,
                              hipStream_t stream) {
  const float* x  = (const float*)d_in[0];
  const int* ei   = (const int*)d_in[1];
  const int* batch = (const int*)d_in[2];
  const float* W1 = (const float*)d_in[3];
  const float* b1 = (const float*)d_in[4];
  const float* W2 = (const float*)d_in[5];
  const float* b2 = (const float*)d_in[6];
  const float* Wg = (const float*)d_in[7];
  const float* bg = (const float*)d_in[8];
  const float* Wf = (const float*)d_in[9];
  const float* bf = (const float*)d_in[10];
  const float* Wo = (const float*)d_in[11];
  const float* bo = (const float*)d_in[12];
  const int* src = ei;
  const int* dst = ei + NE;

  char* p = (char*)d_ws;
  auto alloc4 = [&](size_t units) { void* r = p; p += units * 4; return r; };
  float* dinv  = (float*)alloc4(100224);
  int* cnt     = (int*)alloc4(100224);
  int* off     = (int*)alloc4(100352);
  int* cur     = (int*)alloc4(100224);
  int* bsum    = (int*)alloc4(128);
  int* srcs    = (int*)alloc4(NE);
  unsigned short* xd   = (unsigned short*)alloc4((size_t)NN * 128 / 2);    // 25.6MB
  unsigned short* aggX = (unsigned short*)alloc4((size_t)MPAD * 128 / 2);  // 25.6MB
  unsigned short* td   = (unsigned short*)alloc4((size_t)MPAD * 128 / 2);  // 25.6MB
  unsigned short* h1   = (unsigned short*)alloc4((size_t)MPAD * 256 / 2);  // 51.2MB
  unsigned short* Bt1h = (unsigned short*)alloc4(256 * 128 / 2);
  unsigned short* Bt1l = (unsigned short*)alloc4(256 * 128 / 2);
  unsigned short* Bt2h = (unsigned short*)alloc4(128 * 256 / 2);
  unsigned short* Bt2l = (unsigned short*)alloc4(128 * 256 / 2);
  float* pooled = (float*)alloc4((size_t)NG * F2);
  float* agg2   = (float*)h1;  // alias: h1 dead after GEMM2 (51.2MB)

  hipMemsetAsync(cnt, 0, 100224 * sizeof(int), stream);
  hipMemsetAsync(pooled, 0, (size_t)NG * F2 * sizeof(float), stream);

  // CSR build (shared by both conv layers)
  k_count<<<(NE + 255) / 256, 256, 0, stream>>>(dst, cnt);
  k_dinv<<<(NN + 255) / 256, 256, 0, stream>>>(cnt, dinv);
  k_scan1<<<NB, SCAN_T, 0, stream>>>(cnt, off, bsum);
  k_scan2<<<1, 64, 0, stream>>>(bsum);
  k_scan3<<<(NN + 256) / 256, 256, 0, stream>>>(off, bsum, cur);
  k_place<<<(NE + 255) / 256, 256, 0, stream>>>(src, dst, cur, srcs);

  // weight prep (fp16 hi/lo, transposed, zero-padded)
  k_prepB<<<256, 128, 0, stream>>>(W1, Bt1h, Bt1l, F0, F1, 128);
  k_prepB<<<128, 256, 0, stream>>>(W2, Bt2h, Bt2l, F1, F2, 256);

  // layer 1: fp16 table, gather (fp16 out), MFMA GEMM -> h1 fp16
  k_prepx<<<NN, 128, 0, stream>>>(x, dinv, xd);
  k_gather1<<<NN, 128, 0, stream>>>(xd, dinv, off, srcs, aggX);
  k_mgemm<2, true><<<dim3(2, MPAD / 128), 256, 0, stream>>>(
      aggX, Bt1h, Bt1l, b1, nullptr, F1, h1);

  // layer 2: MFMA GEMM -> td (fp16, dinv folded), then gather
  k_mgemm<4, false><<<dim3(1, MPAD / 128), 256, 0, stream>>>(
      h1, Bt2h, Bt2l, nullptr, dinv, F2, td);
  k_gather2<<<NN, 128, 0, stream>>>(td, dinv, off, srcs, agg2);

  // fused relu(agg2 + b2) + per-graph max pool
  k_pool<<<(NN + POOL_CHUNK - 1) / POOL_CHUNK, 128, 0, stream>>>(agg2, b2, batch, pooled);

  // head MLP
  k_mlp<<<NG, 64, 0, stream>>>(pooled, Wg, bg, Wf, bf, Wo, bo, (float*)d_out);
}

// Round 7
// 345.051 us; speedup vs baseline: 1.5390x; 1.3731x over previous
//
#include <hip/hip_runtime.h>
#include <hip/hip_bf16.h>
#include <hip/hip_fp16.h>

#define NN 100000
#define NG 256
#define NE 800000

constexpr int F0 = 114;   // x features
constexpr int F1 = 230;   // layer1 output features
constexpr int F2 = 115;   // layer2 output features
constexpr int MPAD = 100096;  // 782 * 128

typedef _Float16 __attribute__((ext_vector_type(8))) f16x8;   // MFMA operand
typedef __attribute__((ext_vector_type(4))) float f32x4;      // MFMA acc
typedef __attribute__((ext_vector_type(8))) unsigned short u16x8;

__device__ __forceinline__ unsigned short f2h_bits(float x) {
  _Float16 h = (_Float16)x;
  return __builtin_bit_cast(unsigned short, h);
}
__device__ __forceinline__ float h_bits2f(unsigned short u) {
  return (float)__builtin_bit_cast(_Float16, u);
}

// ---------------- degree / CSR build ----------------

__global__ void k_count(const int* __restrict__ dst, int* __restrict__ cnt) {
  int e = blockIdx.x * blockDim.x + threadIdx.x;
  if (e < NE) atomicAdd(&cnt[dst[e]], 1);
}

__global__ void k_dinv(const int* __restrict__ cnt, float* __restrict__ dinv) {
  int i = blockIdx.x * blockDim.x + threadIdx.x;
  if (i < NN) dinv[i] = rsqrtf((float)cnt[i] + 1.0f);
}

constexpr int SCAN_T = 256;
constexpr int SCAN_E = 1024;
constexpr int NB = (NN + SCAN_E - 1) / SCAN_E;  // 98

__global__ void k_scan1(const int* __restrict__ cnt, int* __restrict__ off,
                        int* __restrict__ bsum) {
  __shared__ int s[SCAN_T];
  int b = blockIdx.x, t = threadIdx.x;
  int base = b * SCAN_E + t * 4;
  int v0 = 0, v1 = 0, v2 = 0, v3 = 0;
  if (base + 0 < NN) v0 = cnt[base + 0];
  if (base + 1 < NN) v1 = cnt[base + 1];
  if (base + 2 < NN) v2 = cnt[base + 2];
  if (base + 3 < NN) v3 = cnt[base + 3];
  int sum = v0 + v1 + v2 + v3;
  s[t] = sum;
  __syncthreads();
  for (int ofs = 1; ofs < SCAN_T; ofs <<= 1) {
    int x = (t >= ofs) ? s[t - ofs] : 0;
    __syncthreads();
    s[t] += x;
    __syncthreads();
  }
  int excl = s[t] - sum;
  if (base + 0 < NN) off[base + 0] = excl;
  if (base + 1 < NN) off[base + 1] = excl + v0;
  if (base + 2 < NN) off[base + 2] = excl + v0 + v1;
  if (base + 3 < NN) off[base + 3] = excl + v0 + v1 + v2;
  if (t == SCAN_T - 1) bsum[b] = s[t];
}

__global__ void k_scan2(int* bsum) {
  if (threadIdx.x == 0) {
    int run = 0;
    for (int i = 0; i < NB; ++i) { int v = bsum[i]; bsum[i] = run; run += v; }
  }
}

__global__ void k_scan3(int* __restrict__ off, const int* __restrict__ bsum,
                        int* __restrict__ cur) {
  int i = blockIdx.x * blockDim.x + threadIdx.x;
  if (i < NN) {
    int v = off[i] + bsum[i / SCAN_E];
    off[i] = v;
    cur[i] = v;
  }
  if (i == NN) off[NN] = NE;
}

__global__ void k_place(const int* __restrict__ src, const int* __restrict__ dst,
                        int* __restrict__ cur, int* __restrict__ srcs) {
  int e = blockIdx.x * blockDim.x + threadIdx.x;
  if (e >= NE) return;
  int p = atomicAdd(&cur[dst[e]], 1);
  srcs[p] = src[e];
}

// ---------------- fp16 tables ----------------

// xd[n,f] = fp16(x[n,f] * dinv[n]), padded to 128 cols
__global__ void k_prepx(const float* __restrict__ x, const float* __restrict__ dinv,
                        unsigned short* __restrict__ xd) {
  int n = blockIdx.x, f = threadIdx.x;  // 128 threads
  float v = (f < F0) ? x[(size_t)n * F0 + f] * dinv[n] : 0.0f;
  xd[(size_t)n * 128 + f] = f2h_bits(v);
}

// ---------------- wave-per-node gather: 4 edges in flight, 1KB/wave-load ----
// acc[n] = tab[n] + sum_j tab[srcs[j]]   (self appended as edge j1)
// POOL=false: out fp16 = acc * dinv[n]  (layer-1 aggX)
// POOL=true:  fused relu(acc*dinv + b2) -> block max -> atomicMax pooled

template <bool POOL>
__global__ __launch_bounds__(256) void k_gatherw(
    const unsigned short* __restrict__ tab, const float* __restrict__ dinv,
    const int* __restrict__ off, const int* __restrict__ srcs,
    const float* __restrict__ b2, const int* __restrict__ batch,
    unsigned short* __restrict__ outh, float* __restrict__ pooled) {
  __shared__ float smax[4][128];
  __shared__ int sg[4];
  int w = threadIdx.x >> 6, lane = threadIdx.x & 63;
  int n = blockIdx.x * 4 + w;
  int grp = lane >> 4, sub = lane & 15;
  int fb = sub * 8;

  float acc[8] = {0.f, 0.f, 0.f, 0.f, 0.f, 0.f, 0.f, 0.f};
  int j0 = off[n], j1 = off[n + 1];
  for (int base = j0; base <= j1; base += 4) {
    int je = base + grp;
    int row = -1;
    if (je < j1) row = srcs[je];
    else if (je == j1) row = n;  // self-loop
    if (row >= 0) {
      u16x8 v = *(const u16x8*)&tab[(size_t)row * 128 + fb];
#pragma unroll
      for (int u = 0; u < 8; ++u) acc[u] += h_bits2f(v[u]);
    }
  }
#pragma unroll
  for (int u = 0; u < 8; ++u) {
    acc[u] += __shfl_xor(acc[u], 16);
    acc[u] += __shfl_xor(acc[u], 32);
  }
  float dn = dinv[n];

  if constexpr (!POOL) {
    if (grp == 0) {
      u16x8 o;
#pragma unroll
      for (int u = 0; u < 8; ++u) o[u] = f2h_bits(acc[u] * dn);
      *(u16x8*)&outh[(size_t)n * 128 + fb] = o;
    }
  } else {
    if (grp == 0) {
#pragma unroll
      for (int u = 0; u < 8; ++u) {
        int f = fb + u;
        float bb = (f < F2) ? b2[f] : 0.0f;
        smax[w][f] = fmaxf(acc[u] * dn + bb, 0.0f);
      }
      if (sub == 0) sg[w] = batch[n];
    }
    __syncthreads();
    int t = threadIdx.x;
    if (t < 128) {
      int g0 = sg[0];
      bool same = (sg[1] == g0) & (sg[2] == g0) & (sg[3] == g0);
      if (same) {
        float m = fmaxf(fmaxf(smax[0][t], smax[1][t]),
                        fmaxf(smax[2][t], smax[3][t]));
        if (t < F2 && m > 0.0f)
          atomicMax((int*)&pooled[g0 * F2 + t], __float_as_int(m));
      } else {
        for (int ww = 0; ww < 4; ++ww) {
          float m = smax[ww][t];
          if (t < F2 && m > 0.0f)
            atomicMax((int*)&pooled[sg[ww] * F2 + t], __float_as_int(m));
        }
      }
    }
  }
}

// ---------------- weight split+transpose prep: Bt[n][k], fp16 hi/lo ----------------

__global__ void k_prepB(const float* __restrict__ W, unsigned short* __restrict__ Bh,
                        unsigned short* __restrict__ Bl, int K, int N, int KP) {
  int n = blockIdx.x, k = threadIdx.x;  // blockDim.x == KP
  float v = (k < K && n < N) ? W[(size_t)k * N + n] : 0.0f;
  unsigned short h = f2h_bits(v);
  unsigned short l = f2h_bits(v - h_bits2f(h));
  Bh[(size_t)n * KP + k] = h;
  Bl[(size_t)n * KP + k] = l;
}

// ---------------- fp16x2 MFMA GEMM: C = A @ (Bh+Bl)^T ----------------
// A fp16 single (exact as stored); weights fp16 hi/lo (~22-bit).
// L1: +bias, relu, out stride 256 at col n0. !L1: *dscale[m], out stride 128.
// 128x128 tile, 4 waves, BK=64 chunks. LDS 55.3 KB -> 2 blocks/CU.

template <int KC64, bool L1>
__global__ __launch_bounds__(256) void k_mgemm(
    const unsigned short* __restrict__ A,
    const unsigned short* __restrict__ Bh, const unsigned short* __restrict__ Bl,
    const float* __restrict__ bias, const float* __restrict__ dscale,
    int Nvalid, unsigned short* __restrict__ C) {
  constexpr int KP = KC64 * 64;
  constexpr int LD = 72;  // ushort stride: 144B rows -> 2-way bank aliasing (free)
  __shared__ unsigned short lds[3 * 128 * LD];  // As | Bsh | Bsl; epilogue reuses
  unsigned short* As  = lds;
  unsigned short* Bsh = lds + 128 * LD;
  unsigned short* Bsl = lds + 2 * 128 * LD;

  int t = threadIdx.x;
  int m0 = blockIdx.y * 128, n0 = blockIdx.x * 128;
  int lane = t & 63, w = t >> 6;
  int wr = (w >> 1) * 64, wc = (w & 1) * 64;
  int r = lane & 15, kb = (lane >> 4) * 8;

  f32x4 acc[4][4];
#pragma unroll
  for (int i = 0; i < 4; ++i)
#pragma unroll
    for (int j = 0; j < 4; ++j) acc[i][j] = (f32x4){0.f, 0.f, 0.f, 0.f};

  int srow = t >> 1, shalf = t & 1;  // 128 rows x 2 halves (32 ushort each)
  int slo = srow * LD + shalf * 32;

  for (int kc = 0; kc < KC64; ++kc) {
    if (kc) __syncthreads();
    size_t ga = (size_t)(m0 + srow) * KP + kc * 64 + shalf * 32;
    size_t gb = (size_t)(n0 + srow) * KP + kc * 64 + shalf * 32;
#pragma unroll
    for (int v = 0; v < 4; ++v) {
      *(u16x8*)&As[slo + v * 8]  = *(const u16x8*)&A[ga + v * 8];
      *(u16x8*)&Bsh[slo + v * 8] = *(const u16x8*)&Bh[gb + v * 8];
      *(u16x8*)&Bsl[slo + v * 8] = *(const u16x8*)&Bl[gb + v * 8];
    }
    __syncthreads();

#pragma unroll
    for (int ks = 0; ks < 2; ++ks) {
      int col = ks * 32 + kb;
      f16x8 a[4], bh[4], bl[4];
#pragma unroll
      for (int i = 0; i < 4; ++i) {
        a[i]  = *(const f16x8*)&As[(wr + i * 16 + r) * LD + col];
        bh[i] = *(const f16x8*)&Bsh[(wc + i * 16 + r) * LD + col];
        bl[i] = *(const f16x8*)&Bsl[(wc + i * 16 + r) * LD + col];
      }
      // lo pass first (small terms), then hi
#pragma unroll
      for (int i = 0; i < 4; ++i)
#pragma unroll
        for (int j = 0; j < 4; ++j)
          acc[i][j] = __builtin_amdgcn_mfma_f32_16x16x32_f16(a[i], bl[j], acc[i][j], 0, 0, 0);
#pragma unroll
      for (int i = 0; i < 4; ++i)
#pragma unroll
        for (int j = 0; j < 4; ++j)
          acc[i][j] = __builtin_amdgcn_mfma_f32_16x16x32_f16(a[i], bh[j], acc[i][j], 0, 0, 0);
    }
  }

  // epilogue: stage fp16 tile in LDS (aliases staging bufs), write coalesced.
  // C/D layout: col = lane&15, row = (lane>>4)*4 + q  [m89/m91]
  __syncthreads();
  constexpr int SW = 136;  // 272B rows: 16B-aligned, 2-way bank aliasing
  unsigned short* sw = lds;
  int rq = (lane >> 4) * 4;
#pragma unroll
  for (int i = 0; i < 4; ++i) {
#pragma unroll
    for (int j = 0; j < 4; ++j) {
      int nl = wc + j * 16 + r;
#pragma unroll
      for (int q = 0; q < 4; ++q) {
        int ml = wr + i * 16 + rq + q;
        float v = acc[i][j][q];
        if constexpr (L1) {
          int n = n0 + nl;
          v = (n < Nvalid) ? fmaxf(v + bias[n], 0.0f) : 0.0f;
        } else {
          v *= dscale[m0 + ml];
        }
        sw[ml * SW + nl] = f2h_bits(v);
      }
    }
  }
  __syncthreads();
  int row = t >> 1, half = t & 1;
  const unsigned short* s = &sw[row * SW + half * 64];
  size_t dst = L1 ? ((size_t)(m0 + row) * 256 + n0 + half * 64)
                  : ((size_t)(m0 + row) * 128 + half * 64);
#pragma unroll
  for (int v = 0; v < 8; ++v)
    *(u16x8*)&C[dst + v * 8] = *(const u16x8*)&s[v * 8];
}

// ---------------- tiny MLP head: 115 -> 64 -> 32 -> 1 ----------------

__global__ void k_mlp(const float* __restrict__ pooled,
                      const float* __restrict__ Wg, const float* __restrict__ bg,
                      const float* __restrict__ Wf, const float* __restrict__ bf,
                      const float* __restrict__ Wo, const float* __restrict__ bo,
                      float* __restrict__ out) {
  __shared__ float sp[F2];
  __shared__ float sg[64];
  __shared__ float sf[32];
  int g = blockIdx.x, t = threadIdx.x;
  for (int f = t; f < F2; f += 64) sp[f] = pooled[g * F2 + f];
  __syncthreads();
  float a = bg[t];
  for (int k = 0; k < F2; ++k) a += sp[k] * Wg[k * 64 + t];
  sg[t] = fmaxf(a, 0.0f);
  __syncthreads();
  if (t < 32) {
    float c = bf[t];
    for (int k = 0; k < 64; ++k) c += sg[k] * Wf[k * 32 + t];
    sf[t] = fmaxf(c, 0.0f);
  }
  __syncthreads();
  if (t == 0) {
    float c = bo[0];
    for (int k = 0; k < 32; ++k) c += sf[k] * Wo[k];
    out[g] = c;
  }
}

// ---------------- launch ----------------

extern "C" void kernel_launch(void* const* d_in, const int* in_sizes, int n_in,
                              void* d_out, int out_size, void* d_ws, size_t ws_size,
                              hipStream_t stream) {
  const float* x  = (const float*)d_in[0];
  const int* ei   = (const int*)d_in[1];
  const int* batch = (const int*)d_in[2];
  const float* W1 = (const float*)d_in[3];
  const float* b1 = (const float*)d_in[4];
  const float* W2 = (const float*)d_in[5];
  const float* b2 = (const float*)d_in[6];
  const float* Wg = (const float*)d_in[7];
  const float* bg = (const float*)d_in[8];
  const float* Wf = (const float*)d_in[9];
  const float* bf = (const float*)d_in[10];
  const float* Wo = (const float*)d_in[11];
  const float* bo = (const float*)d_in[12];
  const int* src = ei;
  const int* dst = ei + NE;

  char* p = (char*)d_ws;
  auto alloc4 = [&](size_t units) { void* r = p; p += units * 4; return r; };
  float* dinv  = (float*)alloc4(100224);
  int* cnt     = (int*)alloc4(100224);
  int* off     = (int*)alloc4(100352);
  int* cur     = (int*)alloc4(100224);
  int* bsum    = (int*)alloc4(128);
  int* srcs    = (int*)alloc4(NE);
  unsigned short* xd   = (unsigned short*)alloc4((size_t)NN * 128 / 2);    // 25.6MB
  unsigned short* aggX = (unsigned short*)alloc4((size_t)MPAD * 128 / 2);  // 25.6MB
  unsigned short* td   = (unsigned short*)alloc4((size_t)MPAD * 128 / 2);  // 25.6MB
  unsigned short* h1   = (unsigned short*)alloc4((size_t)MPAD * 256 / 2);  // 51.2MB
  unsigned short* Bt1h = (unsigned short*)alloc4(256 * 128 / 2);
  unsigned short* Bt1l = (unsigned short*)alloc4(256 * 128 / 2);
  unsigned short* Bt2h = (unsigned short*)alloc4(128 * 256 / 2);
  unsigned short* Bt2l = (unsigned short*)alloc4(128 * 256 / 2);
  float* pooled = (float*)alloc4((size_t)NG * F2);

  hipMemsetAsync(cnt, 0, 100224 * sizeof(int), stream);
  hipMemsetAsync(pooled, 0, (size_t)NG * F2 * sizeof(float), stream);

  // CSR build (shared by both conv layers)
  k_count<<<(NE + 255) / 256, 256, 0, stream>>>(dst, cnt);
  k_dinv<<<(NN + 255) / 256, 256, 0, stream>>>(cnt, dinv);
  k_scan1<<<NB, SCAN_T, 0, stream>>>(cnt, off, bsum);
  k_scan2<<<1, 64, 0, stream>>>(bsum);
  k_scan3<<<(NN + 256) / 256, 256, 0, stream>>>(off, bsum, cur);
  k_place<<<(NE + 255) / 256, 256, 0, stream>>>(src, dst, cur, srcs);

  // weight prep (fp16 hi/lo, transposed, zero-padded)
  k_prepB<<<256, 128, 0, stream>>>(W1, Bt1h, Bt1l, F0, F1, 128);
  k_prepB<<<128, 256, 0, stream>>>(W2, Bt2h, Bt2l, F1, F2, 256);

  // layer 1: fp16 table, wave-per-node gather -> aggX fp16, MFMA GEMM -> h1 fp16
  k_prepx<<<NN, 128, 0, stream>>>(x, dinv, xd);
  k_gatherw<false><<<NN / 4, 256, 0, stream>>>(xd, dinv, off, srcs,
                                               nullptr, nullptr, aggX, nullptr);
  k_mgemm<2, true><<<dim3(2, MPAD / 128), 256, 0, stream>>>(
      aggX, Bt1h, Bt1l, b1, nullptr, F1, h1);

  // layer 2: MFMA GEMM -> td (fp16, dinv folded), then fused gather+pool
  k_mgemm<4, false><<<dim3(1, MPAD / 128), 256, 0, stream>>>(
      h1, Bt2h, Bt2l, nullptr, dinv, F2, td);
  k_gatherw<true><<<NN / 4, 256, 0, stream>>>(td, dinv, off, srcs,
                                              b2, batch, nullptr, pooled);

  // head MLP
  k_mlp<<<NG, 64, 0, stream>>>(pooled, Wg, bg, Wf, bf, Wo, bo, (float*)d_out);
}

// Round 8
// 329.893 us; speedup vs baseline: 1.6097x; 1.0459x over previous
//
#include <hip/hip_runtime.h>
#include <hip/hip_bf16.h>
#include <hip/hip_fp16.h>

#define NN 100000
#define NG 256
#define NE 800000

constexpr int F0 = 114;   // x features
constexpr int F1 = 230;   // layer1 output features
constexpr int F2 = 115;   // layer2 output features
constexpr int MPAD = 100096;  // 782 * 128

typedef _Float16 __attribute__((ext_vector_type(8))) f16x8;   // MFMA operand
typedef __attribute__((ext_vector_type(4))) float f32x4;      // MFMA acc
typedef __attribute__((ext_vector_type(8))) unsigned short u16x8;

__device__ __forceinline__ unsigned short f2h_bits(float x) {
  _Float16 h = (_Float16)x;
  return __builtin_bit_cast(unsigned short, h);
}
__device__ __forceinline__ float h_bits2f(unsigned short u) {
  return (float)__builtin_bit_cast(_Float16, u);
}

// ---------------- degree / CSR build ----------------

__global__ void k_count(const int* __restrict__ dst, int* __restrict__ cnt) {
  int e = blockIdx.x * blockDim.x + threadIdx.x;
  if (e < NE) atomicAdd(&cnt[dst[e]], 1);
}

__global__ void k_dinv(const int* __restrict__ cnt, float* __restrict__ dinv) {
  int i = blockIdx.x * blockDim.x + threadIdx.x;
  if (i < NN) dinv[i] = rsqrtf((float)cnt[i] + 1.0f);
}

constexpr int SCAN_T = 256;
constexpr int SCAN_E = 1024;
constexpr int NB = (NN + SCAN_E - 1) / SCAN_E;  // 98

__global__ void k_scan1(const int* __restrict__ cnt, int* __restrict__ off,
                        int* __restrict__ bsum) {
  __shared__ int s[SCAN_T];
  int b = blockIdx.x, t = threadIdx.x;
  int base = b * SCAN_E + t * 4;
  int v0 = 0, v1 = 0, v2 = 0, v3 = 0;
  if (base + 0 < NN) v0 = cnt[base + 0];
  if (base + 1 < NN) v1 = cnt[base + 1];
  if (base + 2 < NN) v2 = cnt[base + 2];
  if (base + 3 < NN) v3 = cnt[base + 3];
  int sum = v0 + v1 + v2 + v3;
  s[t] = sum;
  __syncthreads();
  for (int ofs = 1; ofs < SCAN_T; ofs <<= 1) {
    int x = (t >= ofs) ? s[t - ofs] : 0;
    __syncthreads();
    s[t] += x;
    __syncthreads();
  }
  int excl = s[t] - sum;
  if (base + 0 < NN) off[base + 0] = excl;
  if (base + 1 < NN) off[base + 1] = excl + v0;
  if (base + 2 < NN) off[base + 2] = excl + v0 + v1;
  if (base + 3 < NN) off[base + 3] = excl + v0 + v1 + v2;
  if (t == SCAN_T - 1) bsum[b] = s[t];
}

__global__ void k_scan2(int* bsum) {
  if (threadIdx.x == 0) {
    int run = 0;
    for (int i = 0; i < NB; ++i) { int v = bsum[i]; bsum[i] = run; run += v; }
  }
}

__global__ void k_scan3(int* __restrict__ off, const int* __restrict__ bsum,
                        int* __restrict__ cur) {
  int i = blockIdx.x * blockDim.x + threadIdx.x;
  if (i < NN) {
    int v = off[i] + bsum[i / SCAN_E];
    off[i] = v;
    cur[i] = v;
  }
  if (i == NN) off[NN] = NE;
}

__global__ void k_place(const int* __restrict__ src, const int* __restrict__ dst,
                        int* __restrict__ cur, int* __restrict__ srcs) {
  int e = blockIdx.x * blockDim.x + threadIdx.x;
  if (e >= NE) return;
  int p = atomicAdd(&cur[dst[e]], 1);
  srcs[p] = src[e];
}

// ---------------- fp16 tables ----------------

// xd[n,f] = fp16(x[n,f] * dinv[n]), padded to 128 cols
__global__ void k_prepx(const float* __restrict__ x, const float* __restrict__ dinv,
                        unsigned short* __restrict__ xd) {
  int n = blockIdx.x, f = threadIdx.x;  // 128 threads
  float v = (f < F0) ? x[(size_t)n * F0 + f] * dinv[n] : 0.0f;
  xd[(size_t)n * 128 + f] = f2h_bits(v);
}

// ---------------- wave-per-node gather: 8 edges/iter, 2 loads in flight ----
// acc[n] = tab[n] + sum_j tab[srcs[j]]   (self appended as edge j1)
// POOL=false: out fp16 = acc * dinv[n]  (layer-1 aggX)
// POOL=true:  fused relu(acc*dinv + b2) -> block max -> atomicMax pooled

template <bool POOL>
__global__ __launch_bounds__(256) void k_gatherw(
    const unsigned short* __restrict__ tab, const float* __restrict__ dinv,
    const int* __restrict__ off, const int* __restrict__ srcs,
    const float* __restrict__ b2, const int* __restrict__ batch,
    unsigned short* __restrict__ outh, float* __restrict__ pooled) {
  __shared__ float smax[4][128];
  __shared__ int sg[4];
  int w = threadIdx.x >> 6, lane = threadIdx.x & 63;
  int n = blockIdx.x * 4 + w;
  int grp = lane >> 4, sub = lane & 15;
  int fb = sub * 8;

  float acc[8] = {0.f, 0.f, 0.f, 0.f, 0.f, 0.f, 0.f, 0.f};
  int j0 = off[n], j1 = off[n + 1];  // slots j0..j1, self at j1
  for (int base = j0; base <= j1; base += 8) {
    int je0 = base + grp;
    int je1 = base + 4 + grp;
    int row0 = (je0 < j1) ? srcs[je0] : ((je0 == j1) ? n : -1);
    int row1 = (je1 < j1) ? srcs[je1] : ((je1 == j1) ? n : -1);
    u16x8 v0, v1;
    bool has0 = row0 >= 0, has1 = row1 >= 0;
    // issue both loads before consuming either (2 KB/wave in flight)
    if (has0) v0 = *(const u16x8*)&tab[(size_t)row0 * 128 + fb];
    if (has1) v1 = *(const u16x8*)&tab[(size_t)row1 * 128 + fb];
    if (has0) {
#pragma unroll
      for (int u = 0; u < 8; ++u) acc[u] += h_bits2f(v0[u]);
    }
    if (has1) {
#pragma unroll
      for (int u = 0; u < 8; ++u) acc[u] += h_bits2f(v1[u]);
    }
  }
#pragma unroll
  for (int u = 0; u < 8; ++u) {
    acc[u] += __shfl_xor(acc[u], 16);
    acc[u] += __shfl_xor(acc[u], 32);
  }
  float dn = dinv[n];

  if constexpr (!POOL) {
    if (grp == 0) {
      u16x8 o;
#pragma unroll
      for (int u = 0; u < 8; ++u) o[u] = f2h_bits(acc[u] * dn);
      *(u16x8*)&outh[(size_t)n * 128 + fb] = o;
    }
  } else {
    if (grp == 0) {
#pragma unroll
      for (int u = 0; u < 8; ++u) {
        int f = fb + u;
        float bb = (f < F2) ? b2[f] : 0.0f;
        smax[w][f] = fmaxf(acc[u] * dn + bb, 0.0f);
      }
      if (sub == 0) sg[w] = batch[n];
    }
    __syncthreads();
    int t = threadIdx.x;
    if (t < 128) {
      int g0 = sg[0];
      bool same = (sg[1] == g0) & (sg[2] == g0) & (sg[3] == g0);
      if (same) {
        float m = fmaxf(fmaxf(smax[0][t], smax[1][t]),
                        fmaxf(smax[2][t], smax[3][t]));
        if (t < F2 && m > 0.0f)
          atomicMax((int*)&pooled[g0 * F2 + t], __float_as_int(m));
      } else {
        for (int ww = 0; ww < 4; ++ww) {
          float m = smax[ww][t];
          if (t < F2 && m > 0.0f)
            atomicMax((int*)&pooled[sg[ww] * F2 + t], __float_as_int(m));
        }
      }
    }
  }
}

// ---------------- weight split+transpose prep: Bt[n][k], fp16 hi/lo ----------------

__global__ void k_prepB(const float* __restrict__ W, unsigned short* __restrict__ Bh,
                        unsigned short* __restrict__ Bl, int K, int N, int KP) {
  int n = blockIdx.x, k = threadIdx.x;  // blockDim.x == KP
  float v = (k < K && n < N) ? W[(size_t)k * N + n] : 0.0f;
  unsigned short h = f2h_bits(v);
  unsigned short l = f2h_bits(v - h_bits2f(h));
  Bh[(size_t)n * KP + k] = h;
  Bl[(size_t)n * KP + k] = l;
}

// ---------------- fp16x2 MFMA GEMM: C = A @ (Bh+Bl)^T ----------------
// A fp16 single (exact as stored); weights fp16 hi/lo (~22-bit).
// L1: +bias, relu, out stride 256 at col n0. !L1: *dscale[m], out stride 128.
// 128x128 tile, 4 waves, BK=64 chunks. LDS 55.3 KB -> 2 blocks/CU.

template <int KC64, bool L1>
__global__ __launch_bounds__(256) void k_mgemm(
    const unsigned short* __restrict__ A,
    const unsigned short* __restrict__ Bh, const unsigned short* __restrict__ Bl,
    const float* __restrict__ bias, const float* __restrict__ dscale,
    int Nvalid, unsigned short* __restrict__ C) {
  constexpr int KP = KC64 * 64;
  constexpr int LD = 72;  // ushort stride: 144B rows -> 2-way bank aliasing (free)
  __shared__ unsigned short lds[3 * 128 * LD];  // As | Bsh | Bsl; epilogue reuses
  unsigned short* As  = lds;
  unsigned short* Bsh = lds + 128 * LD;
  unsigned short* Bsl = lds + 2 * 128 * LD;

  int t = threadIdx.x;
  int m0 = blockIdx.y * 128, n0 = blockIdx.x * 128;
  int lane = t & 63, w = t >> 6;
  int wr = (w >> 1) * 64, wc = (w & 1) * 64;
  int r = lane & 15, kb = (lane >> 4) * 8;

  f32x4 acc[4][4];
#pragma unroll
  for (int i = 0; i < 4; ++i)
#pragma unroll
    for (int j = 0; j < 4; ++j) acc[i][j] = (f32x4){0.f, 0.f, 0.f, 0.f};

  int srow = t >> 1, shalf = t & 1;  // 128 rows x 2 halves (32 ushort each)
  int slo = srow * LD + shalf * 32;

  for (int kc = 0; kc < KC64; ++kc) {
    if (kc) __syncthreads();
    size_t ga = (size_t)(m0 + srow) * KP + kc * 64 + shalf * 32;
    size_t gb = (size_t)(n0 + srow) * KP + kc * 64 + shalf * 32;
#pragma unroll
    for (int v = 0; v < 4; ++v) {
      *(u16x8*)&As[slo + v * 8]  = *(const u16x8*)&A[ga + v * 8];
      *(u16x8*)&Bsh[slo + v * 8] = *(const u16x8*)&Bh[gb + v * 8];
      *(u16x8*)&Bsl[slo + v * 8] = *(const u16x8*)&Bl[gb + v * 8];
    }
    __syncthreads();

#pragma unroll
    for (int ks = 0; ks < 2; ++ks) {
      int col = ks * 32 + kb;
      f16x8 a[4], bh[4], bl[4];
#pragma unroll
      for (int i = 0; i < 4; ++i) {
        a[i]  = *(const f16x8*)&As[(wr + i * 16 + r) * LD + col];
        bh[i] = *(const f16x8*)&Bsh[(wc + i * 16 + r) * LD + col];
        bl[i] = *(const f16x8*)&Bsl[(wc + i * 16 + r) * LD + col];
      }
      // lo pass first (small terms), then hi
#pragma unroll
      for (int i = 0; i < 4; ++i)
#pragma unroll
        for (int j = 0; j < 4; ++j)
          acc[i][j] = __builtin_amdgcn_mfma_f32_16x16x32_f16(a[i], bl[j], acc[i][j], 0, 0, 0);
#pragma unroll
      for (int i = 0; i < 4; ++i)
#pragma unroll
        for (int j = 0; j < 4; ++j)
          acc[i][j] = __builtin_amdgcn_mfma_f32_16x16x32_f16(a[i], bh[j], acc[i][j], 0, 0, 0);
    }
  }

  // epilogue: stage fp16 tile in LDS (aliases staging bufs), write coalesced.
  // C/D layout: col = lane&15, row = (lane>>4)*4 + q  [m89/m91]
  __syncthreads();
  constexpr int SW = 136;  // 272B rows: 16B-aligned, 2-way bank aliasing
  unsigned short* sw = lds;
  int rq = (lane >> 4) * 4;
#pragma unroll
  for (int i = 0; i < 4; ++i) {
#pragma unroll
    for (int j = 0; j < 4; ++j) {
      int nl = wc + j * 16 + r;
#pragma unroll
      for (int q = 0; q < 4; ++q) {
        int ml = wr + i * 16 + rq + q;
        float v = acc[i][j][q];
        if constexpr (L1) {
          int n = n0 + nl;
          v = (n < Nvalid) ? fmaxf(v + bias[n], 0.0f) : 0.0f;
        } else {
          v *= dscale[m0 + ml];
        }
        sw[ml * SW + nl] = f2h_bits(v);
      }
    }
  }
  __syncthreads();
  int row = t >> 1, half = t & 1;
  const unsigned short* s = &sw[row * SW + half * 64];
  size_t dst = L1 ? ((size_t)(m0 + row) * 256 + n0 + half * 64)
                  : ((size_t)(m0 + row) * 128 + half * 64);
#pragma unroll
  for (int v = 0; v < 8; ++v)
    *(u16x8*)&C[dst + v * 8] = *(const u16x8*)&s[v * 8];
}

// ---------------- tiny MLP head: 115 -> 64 -> 32 -> 1 ----------------

__global__ void k_mlp(const float* __restrict__ pooled,
                      const float* __restrict__ Wg, const float* __restrict__ bg,
                      const float* __restrict__ Wf, const float* __restrict__ bf,
                      const float* __restrict__ Wo, const float* __restrict__ bo,
                      float* __restrict__ out) {
  __shared__ float sp[F2];
  __shared__ float sg[64];
  __shared__ float sf[32];
  int g = blockIdx.x, t = threadIdx.x;
  for (int f = t; f < F2; f += 64) sp[f] = pooled[g * F2 + f];
  __syncthreads();
  float a = bg[t];
  for (int k = 0; k < F2; ++k) a += sp[k] * Wg[k * 64 + t];
  sg[t] = fmaxf(a, 0.0f);
  __syncthreads();
  if (t < 32) {
    float c = bf[t];
    for (int k = 0; k < 64; ++k) c += sg[k] * Wf[k * 32 + t];
    sf[t] = fmaxf(c, 0.0f);
  }
  __syncthreads();
  if (t == 0) {
    float c = bo[0];
    for (int k = 0; k < 32; ++k) c += sf[k] * Wo[k];
    out[g] = c;
  }
}

// ---------------- launch ----------------

extern "C" void kernel_launch(void* const* d_in, const int* in_sizes, int n_in,
                              void* d_out, int out_size, void* d_ws, size_t ws_size,
                              hipStream_t stream) {
  const float* x  = (const float*)d_in[0];
  const int* ei   = (const int*)d_in[1];
  const int* batch = (const int*)d_in[2];
  const float* W1 = (const float*)d_in[3];
  const float* b1 = (const float*)d_in[4];
  const float* W2 = (const float*)d_in[5];
  const float* b2 = (const float*)d_in[6];
  const float* Wg = (const float*)d_in[7];
  const float* bg = (const float*)d_in[8];
  const float* Wf = (const float*)d_in[9];
  const float* bf = (const float*)d_in[10];
  const float* Wo = (const float*)d_in[11];
  const float* bo = (const float*)d_in[12];
  const int* src = ei;
  const int* dst = ei + NE;

  char* p = (char*)d_ws;
  auto alloc4 = [&](size_t units) { void* r = p; p += units * 4; return r; };
  float* dinv  = (float*)alloc4(100224);
  int* cnt     = (int*)alloc4(100224);
  int* off     = (int*)alloc4(100352);
  int* cur     = (int*)alloc4(100224);
  int* bsum    = (int*)alloc4(128);
  int* srcs    = (int*)alloc4(NE);
  unsigned short* xd   = (unsigned short*)alloc4((size_t)NN * 128 / 2);    // 25.6MB
  unsigned short* aggX = (unsigned short*)alloc4((size_t)MPAD * 128 / 2);  // 25.6MB
  unsigned short* td   = (unsigned short*)alloc4((size_t)MPAD * 128 / 2);  // 25.6MB
  unsigned short* h1   = (unsigned short*)alloc4((size_t)MPAD * 256 / 2);  // 51.2MB
  unsigned short* Bt1h = (unsigned short*)alloc4(256 * 128 / 2);
  unsigned short* Bt1l = (unsigned short*)alloc4(256 * 128 / 2);
  unsigned short* Bt2h = (unsigned short*)alloc4(128 * 256 / 2);
  unsigned short* Bt2l = (unsigned short*)alloc4(128 * 256 / 2);
  float* pooled = (float*)alloc4((size_t)NG * F2);

  hipMemsetAsync(cnt, 0, 100224 * sizeof(int), stream);
  hipMemsetAsync(pooled, 0, (size_t)NG * F2 * sizeof(float), stream);

  // CSR build (shared by both conv layers)
  k_count<<<(NE + 255) / 256, 256, 0, stream>>>(dst, cnt);
  k_dinv<<<(NN + 255) / 256, 256, 0, stream>>>(cnt, dinv);
  k_scan1<<<NB, SCAN_T, 0, stream>>>(cnt, off, bsum);
  k_scan2<<<1, 64, 0, stream>>>(bsum);
  k_scan3<<<(NN + 256) / 256, 256, 0, stream>>>(off, bsum, cur);
  k_place<<<(NE + 255) / 256, 256, 0, stream>>>(src, dst, cur, srcs);

  // weight prep (fp16 hi/lo, transposed, zero-padded)
  k_prepB<<<256, 128, 0, stream>>>(W1, Bt1h, Bt1l, F0, F1, 128);
  k_prepB<<<128, 256, 0, stream>>>(W2, Bt2h, Bt2l, F1, F2, 256);

  // layer 1: fp16 table, wave-per-node gather -> aggX fp16, MFMA GEMM -> h1 fp16
  k_prepx<<<NN, 128, 0, stream>>>(x, dinv, xd);
  k_gatherw<false><<<NN / 4, 256, 0, stream>>>(xd, dinv, off, srcs,
                                               nullptr, nullptr, aggX, nullptr);
  k_mgemm<2, true><<<dim3(2, MPAD / 128), 256, 0, stream>>>(
      aggX, Bt1h, Bt1l, b1, nullptr, F1, h1);

  // layer 2: MFMA GEMM -> td (fp16, dinv folded), then fused gather+pool
  k_mgemm<4, false><<<dim3(1, MPAD / 128), 256, 0, stream>>>(
      h1, Bt2h, Bt2l, nullptr, dinv, F2, td);
  k_gatherw<true><<<NN / 4, 256, 0, stream>>>(td, dinv, off, srcs,
                                              b2, batch, nullptr, pooled);

  // head MLP
  k_mlp<<<NG, 64, 0, stream>>>(pooled, Wg, bg, Wf, bf, Wo, bo, (float*)d_out);
}